// Round 14
// baseline (452.232 us; speedup 1.0000x reference)
//
#include <hip/hip_runtime.h>
#include <math.h>

typedef unsigned short u16;
typedef __attribute__((ext_vector_type(8))) short frag8;   // 8 bf16 = 4 VGPR
typedef __attribute__((ext_vector_type(4))) float f32x4;   // MFMA acc

__device__ __forceinline__ float eluf(float v) { return v > 0.f ? v : expm1f(v); }
__device__ __forceinline__ float geluf(float v) {
  return 0.5f * v * (1.f + erff(v * 0.70710678118654752f));
}
__device__ __forceinline__ u16 f2bf(float f) {
  union { float f; unsigned int i; } v; v.f = f;
  return (u16)((v.i + 0x7fffu + ((v.i >> 16) & 1u)) >> 16);
}

#define BN_S 0.99999500003749969f   /* 1/sqrt(1+1e-5) */

// ============================================================
// k_tws1 (round-1 measured config)
// ============================================================
__global__ void k_tws1(const float* tw1, const float* tw2, const float* tw3, const float* tw4,
                       const float* tb1, const float* tb2, const float* tb3, const float* tb4,
                       const float* bn1g, const float* bn1b,
                       float* tws1, float* c1) {
  int idx = blockIdx.x * 256 + threadIdx.x;
  if (idx < 8320) {
    int i = idx / 65, u = idx - i * 65;
    int g = i >> 5, il = i & 31;
    const float* tws[4] = {tw1, tw2, tw3, tw4};
    const int P[4] = {7, 12, 25, 32};
    int c = u - 32;
    float s1 = bn1g[i] * BN_S;
    float val = 0.f;
    int p = P[g];
    if (c >= -p && c <= p) val = s1 * tws[g][il * (2 * p + 1) + (c + p)];
    tws1[idx] = val;
  } else if (idx < 8448) {
    int i = idx - 8320;
    int g = i >> 5, il = i & 31;
    const float* tbs[4] = {tb1, tb2, tb3, tb4};
    float s1 = bn1g[i] * BN_S;
    c1[i] = s1 * tbs[g][il] + bn1b[i];
  }
}

// ============================================================
// k_weff (round-1 measured config): one WAVE per (u, o). lane = kh.
// ============================================================
__global__ __launch_bounds__(256) void k_weff(const float* __restrict__ sw, const float* __restrict__ sb,
                                              const float* __restrict__ tws1, const float* __restrict__ c1,
                                              u16* __restrict__ Wb, float* __restrict__ biasEff) {
  const int lane = threadIdx.x & 63, wave = threadIdx.x >> 6;
  const int u = blockIdx.x;
  const int o = blockIdx.y * 4 + wave;
  const float* swp = sw + o * 8192 + lane;     // + i*64
  if (u < 65) {
    const float* tp = tws1 + u;                // + i*65 (wave-uniform)
    float a0 = 0.f, a1 = 0.f, a2 = 0.f, a3 = 0.f;
    #pragma unroll 8
    for (int i = 0; i < 128; i += 4) {
      a0 = fmaf(swp[(i + 0) * 64], tp[(i + 0) * 65], a0);
      a1 = fmaf(swp[(i + 1) * 64], tp[(i + 1) * 65], a1);
      a2 = fmaf(swp[(i + 2) * 64], tp[(i + 2) * 65], a2);
      a3 = fmaf(swp[(i + 3) * 64], tp[(i + 3) * 65], a3);
    }
    Wb[(u * 128 + o) * 64 + lane] = f2bf((a0 + a1) + (a2 + a3));
  } else {
    float pa = 0.f;
    #pragma unroll 8
    for (int i = 0; i < 128; i++)
      pa = fmaf(swp[i * 64], c1[i], pa);
    #pragma unroll
    for (int off = 32; off; off >>= 1) pa += __shfl_xor(pa, off);
    if (lane == 0) biasEff[o] = pa + sb[o];
  }
}

// ============================================================
// k_conv: u-loop SPLIT across 2 blocks. grid (16, 4, 16);
// y = {o-half, u-half}. Block computes u in [u0,u1), writes RAW f32
// partial sums to slab za (uh=0) or zb (uh=1) — EXPLICIT pointers
// (r13 bug: computed slab B as z+2048000 which clobbered X/Wenc).
// k_pool combines slabs + applies bias/bn2/elu.
// ============================================================
__global__ __launch_bounds__(256) void k_conv(const float* __restrict__ x,
                                              const u16* __restrict__ Wb,
                                              float* __restrict__ za, float* __restrict__ zb) {
  __shared__ u16 xs[128 * 88];   // 22.5 KB; row tt -> t0-32+tt, col kh
  const int tid = threadIdx.x;
  const int t0 = blockIdx.x * 64;
  const int o0 = (blockIdx.y & 1) * 64;
  const int uh = blockIdx.y >> 1;
  const int b  = blockIdx.z;
  const int u0 = uh ? 33 : 0;
  const int u1 = uh ? 65 : 33;

  #pragma unroll
  for (int i = 0; i < 8; i++) {
    int pos = tid + i * 256;
    int kh = pos >> 5;
    int tt = (pos & 31) * 4;
    int gt = t0 - 32 + tt;
    const float* xp = x + (b * 64 + kh) * 1000;
    float v[4];
    if (gt >= 0 && gt + 3 < 1000) {
      float4 f = *(const float4*)(xp + gt);
      v[0] = f.x; v[1] = f.y; v[2] = f.z; v[3] = f.w;
    } else {
      #pragma unroll
      for (int e = 0; e < 4; e++) { int g2 = gt + e; v[e] = (g2 >= 0 && g2 < 1000) ? xp[g2] : 0.f; }
    }
    #pragma unroll
    for (int e = 0; e < 4; e++) xs[(tt + e) * 88 + kh] = f2bf(v[e]);
  }
  __syncthreads();

  const int lane = tid & 63, wave = tid >> 6;
  const int wt = (wave & 1) * 32;
  const int wo = (wave >> 1) * 32;
  const int m = lane & 15, q = lane >> 4;

  f32x4 acc[2][2];
  #pragma unroll
  for (int i = 0; i < 2; i++)
    #pragma unroll
    for (int j = 0; j < 2; j++) acc[i][j] = (f32x4){0.f, 0.f, 0.f, 0.f};

  frag8 Bc[2][2];
  #pragma unroll
  for (int op = 0; op < 2; op++)
    #pragma unroll
    for (int kc = 0; kc < 2; kc++)
      Bc[op][kc] = *(const frag8*)(Wb + ((u0 * 128) + o0 + wo + op * 16 + m) * 64 + kc * 32 + q * 8);

  #pragma unroll 1
  for (int u = u0; u < u1; u++) {
    frag8 Bn[2][2];
    int un = (u + 1 < u1) ? u + 1 : u;     // harmless re-load on last iter
    #pragma unroll
    for (int op = 0; op < 2; op++)
      #pragma unroll
      for (int kc = 0; kc < 2; kc++)
        Bn[op][kc] = *(const frag8*)(Wb + ((un * 128) + o0 + wo + op * 16 + m) * 64 + kc * 32 + q * 8);
    frag8 A[2][2];
    #pragma unroll
    for (int tp = 0; tp < 2; tp++)
      #pragma unroll
      for (int kc = 0; kc < 2; kc++)
        A[tp][kc] = *(const frag8*)&xs[(wt + tp * 16 + m + u) * 88 + kc * 32 + q * 8];
    #pragma unroll
    for (int tp = 0; tp < 2; tp++)
      #pragma unroll
      for (int op = 0; op < 2; op++) {
        acc[tp][op] = __builtin_amdgcn_mfma_f32_16x16x32_bf16(A[tp][0], Bc[op][0], acc[tp][op], 0, 0, 0);
        acc[tp][op] = __builtin_amdgcn_mfma_f32_16x16x32_bf16(A[tp][1], Bc[op][1], acc[tp][op], 0, 0, 0);
      }
    #pragma unroll
    for (int op = 0; op < 2; op++)
      #pragma unroll
      for (int kc = 0; kc < 2; kc++)
        Bc[op][kc] = Bn[op][kc];
  }

  float* zp = uh ? zb : za;
  #pragma unroll
  for (int op = 0; op < 2; op++) {
    int o = o0 + wo + op * 16 + m;
    #pragma unroll
    for (int tp = 0; tp < 2; tp++) {
      #pragma unroll
      for (int r = 0; r < 4; r++) {
        int t = t0 + wt + tp * 16 + q * 4 + r;
        if (t < 1000)
          zp[(b * 128 + o) * 1000 + t] = acc[tp][op][r];
      }
    }
  }
}

// ============================================================
// k_pool: combines the two conv partial slabs, applies
// bias/bn2/elu, then mean/log-var pooling (same accumulation order).
// ============================================================
__global__ __launch_bounds__(128) void k_pool(const float* __restrict__ za, const float* __restrict__ zb,
                                              const float* __restrict__ biasEff,
                                              const float* __restrict__ bn2g, const float* __restrict__ bn2b,
                                              float* __restrict__ X) {
  int p = blockIdx.x, b = blockIdx.y, o = threadIdx.x;
  int base = (b * 128 + o) * 1000 + p * 15;
  float s2 = bn2g[o] * BN_S;
  float be = biasEff[o], b2 = bn2b[o];
  float s = 0.f, ss = 0.f;
  #pragma unroll
  for (int k = 0; k < 50; k++) {
    float v = eluf((za[base + k] + zb[base + k] + be) * s2 + b2);
    s += v; ss = fmaf(v, v, ss);
  }
  float m = s * 0.02f;
  float var = (ss - s * m) * (1.f / 49.f);
  var = fminf(fmaxf(var, 1e-6f), 1e6f);
  X[(b * 64 + p) * 128 + o] = m;
  X[((16 + b) * 64 + p) * 128 + o] = logf(var);
}

// ============================================================
// k_cvt6 (round-1 measured config): encoder weights f32 -> bf16
// ============================================================
__global__ __launch_bounds__(256) void k_cvt6(const float* __restrict__ wq, const float* __restrict__ wk,
                                              const float* __restrict__ wv, const float* __restrict__ wo,
                                              const float* __restrict__ f1w, const float* __restrict__ f2w,
                                              u16* __restrict__ out) {
  int i = blockIdx.x * 256 + threadIdx.x;   // float4 index, total 196608
  if (i >= 196608) return;
  int fi = i * 4;
  const float* src; int off;
  if      (fi < 65536)  { src = wq;  off = fi; }
  else if (fi < 131072) { src = wk;  off = fi - 65536; }
  else if (fi < 196608) { src = wv;  off = fi - 131072; }
  else if (fi < 262144) { src = wo;  off = fi - 196608; }
  else if (fi < 524288) { src = f1w; off = fi - 262144; }
  else                  { src = f2w; off = fi - 524288; }
  float4 v = *(const float4*)(src + off);
  ushort4 p;
  p.x = f2bf(v.x); p.y = f2bf(v.y); p.z = f2bf(v.z); p.w = f2bf(v.w);
  *(ushort4*)(out + fi) = p;
}

// ============================================================
// k_enc (round-8 measured config, 115.5 us): fused 4-layer encoder,
// 32 blocks x 512 threads. MFMA attention; 6 barriers/layer.
// LDS (137.2 KB): Xs f32[64][132] | Hs bf16[64][136] | Pool u16[43008]
// ============================================================
__device__ __forceinline__ void ln128(const float* __restrict__ Xs, u16* __restrict__ Hs,
                                      const float* __restrict__ g, const float* __restrict__ b,
                                      int lane, int wave) {
  float g0 = g[lane], g1 = g[64 + lane], b0 = b[lane], b1 = b[64 + lane];
  #pragma unroll
  for (int rr = 0; rr < 8; rr++) {
    int r = wave * 8 + rr;
    float v0 = Xs[r * 132 + lane], v1 = Xs[r * 132 + 64 + lane];
    float s_ = v0 + v1;
    #pragma unroll
    for (int off = 32; off; off >>= 1) s_ += __shfl_xor(s_, off);
    float mn = s_ * (1.f / 128.f);
    float d0 = v0 - mn, d1 = v1 - mn;
    float qq = d0 * d0 + d1 * d1;
    #pragma unroll
    for (int off = 32; off; off >>= 1) qq += __shfl_xor(qq, off);
    float rs = rsqrtf(qq * (1.f / 128.f) + 1e-5f);
    Hs[r * 136 + lane]      = f2bf(d0 * rs * g0 + b0);
    Hs[r * 136 + 64 + lane] = f2bf(d1 * rs * g1 + b1);
  }
}

__device__ __forceinline__ void gemm_hoist(const frag8 Ar[4][4], const frag8 Bf[4], f32x4 acc[4]) {
  #pragma unroll
  for (int kc = 0; kc < 4; kc++)
    #pragma unroll
    for (int mt = 0; mt < 4; mt++)
      acc[mt] = __builtin_amdgcn_mfma_f32_16x16x32_bf16(Ar[mt][kc], Bf[kc], acc[mt], 0, 0, 0);
}

__device__ __forceinline__ void gemm_pref(const u16* __restrict__ Asrc, int astride,
                                          const frag8 Bf[4], int m, int q, f32x4 acc[4]) {
  #pragma unroll
  for (int kc = 0; kc < 4; kc++) {
    #pragma unroll
    for (int mt = 0; mt < 4; mt++) {
      frag8 Af = *(const frag8*)(Asrc + (mt * 16 + m) * astride + kc * 32 + q * 8);
      acc[mt] = __builtin_amdgcn_mfma_f32_16x16x32_bf16(Af, Bf[kc], acc[mt], 0, 0, 0);
    }
  }
}

__global__ __launch_bounds__(512, 1) void k_enc(float* __restrict__ X,
                                                const u16* __restrict__ Wenc,
                                                const float* __restrict__ ln1g, const float* __restrict__ ln1b,
                                                const float* __restrict__ ln2g, const float* __restrict__ ln2b,
                                                const float* __restrict__ bq, const float* __restrict__ bk,
                                                const float* __restrict__ bv, const float* __restrict__ bo,
                                                const float* __restrict__ f1b, const float* __restrict__ f2b) {
  __shared__ __align__(16) float Xs[64 * 132];
  __shared__ __align__(16) u16   Hs[64 * 136];
  __shared__ __align__(16) u16   Pool[43008];
  u16* AOs = Hs;

  const int tid = threadIdx.x;
  const int lane = tid & 63, wave = tid >> 6;
  const int m = lane & 15, q = lane >> 4;
  const int n0 = wave * 16;
  float* Xg = X + blockIdx.x * 64 * 128;

  const u16* WQ  = Wenc;
  const u16* WK  = Wenc + 65536;
  const u16* WV  = Wenc + 131072;
  const u16* WO  = Wenc + 196608;
  const u16* F1W = Wenc + 262144;
  const u16* F2W = Wenc + 524288;

  u16* Qh = Pool + wave * 2048;            // [64][32], zero-padded K
  u16* Kh = Pool + 16384 + wave * 2048;    // [64][32]
  u16* Vh = Pool + 32768 + wave * 1280;    // [16][80] transposed V

  for (int i = tid; i < 8192; i += 512) Xs[(i >> 7) * 132 + (i & 127)] = Xg[i];
  __syncthreads();

  #pragma unroll 1
  for (int l = 0; l < 4; l++) {
    const u16* wqb  = WQ  + l * 16384;
    const u16* wkb  = WK  + l * 16384;
    const u16* wvb  = WV  + l * 16384;
    const u16* wob  = WO  + l * 16384;
    const u16* f1wb = F1W + l * 65536;
    const u16* f2wb = F2W + l * 65536;

    // ---- prefetch QKV B-frags (hide under LN1) ----
    frag8 fq[4], fk[4], fv[4];
    #pragma unroll
    for (int kc = 0; kc < 4; kc++) {
      fq[kc] = *(const frag8*)(wqb + (n0 + m) * 128 + kc * 32 + q * 8);
      fk[kc] = *(const frag8*)(wkb + (n0 + m) * 128 + kc * 32 + q * 8);
      fv[kc] = *(const frag8*)(wvb + (n0 + m) * 128 + kc * 32 + q * 8);
    }

    // ---- LN1 -> Hs ----
    ln128(Xs, Hs, ln1g + l * 128, ln1b + l * 128, lane, wave);
    __syncthreads();                                        // B1

    // ---- QKV gemms (A hoisted) + bf16 stores into head buffers ----
    frag8 fo[4];
    #pragma unroll
    for (int kc = 0; kc < 4; kc++)
      fo[kc] = *(const frag8*)(wob + (n0 + m) * 128 + kc * 32 + q * 8);
    {
      frag8 Ar[4][4];
      #pragma unroll
      for (int mt = 0; mt < 4; mt++)
        #pragma unroll
        for (int kc = 0; kc < 4; kc++)
          Ar[mt][kc] = *(const frag8*)&Hs[(mt * 16 + m) * 136 + kc * 32 + q * 8];
      f32x4 aq[4], ak[4], av[4];
      #pragma unroll
      for (int mt = 0; mt < 4; mt++) { aq[mt] = (f32x4){0,0,0,0}; ak[mt] = (f32x4){0,0,0,0}; av[mt] = (f32x4){0,0,0,0}; }
      gemm_hoist(Ar, fq, aq);
      gemm_hoist(Ar, fk, ak);
      gemm_hoist(Ar, fv, av);
      float bqv = bq[l * 128 + n0 + m];
      float bkv = bk[l * 128 + n0 + m];
      float bvv = bv[l * 128 + n0 + m];
      #pragma unroll
      for (int mt = 0; mt < 4; mt++)
        #pragma unroll
        for (int r = 0; r < 4; r++) {
          int row = mt * 16 + q * 4 + r;
          Qh[row * 32 + m] = f2bf((aq[mt][r] + bqv) * 0.25f);  // fold 1/sqrt(dk), exact
          Kh[row * 32 + m] = f2bf(ak[mt][r] + bkv);
          Vh[m * 80 + row] = f2bf(av[mt][r] + bvv);            // V transposed [d][key]
        }
      frag8 z8 = {};
      *(frag8*)&Qh[lane * 32 + 16] = z8;
      *(frag8*)&Qh[lane * 32 + 24] = z8;
      *(frag8*)&Kh[lane * 32 + 16] = z8;
      *(frag8*)&Kh[lane * 32 + 24] = z8;
    }

    // ---- attention (wave-local head; no barrier since QKV) ----
    frag8 f1f[4];
    #pragma unroll
    for (int kc = 0; kc < 4; kc++)
      f1f[kc] = *(const frag8*)(f1wb + (n0 + m) * 128 + kc * 32 + q * 8);
    {
      f32x4 sacc[4][4];
      frag8 QA[4], KB[4];
      #pragma unroll
      for (int mt = 0; mt < 4; mt++) QA[mt] = *(const frag8*)&Qh[(mt * 16 + m) * 32 + q * 8];
      #pragma unroll
      for (int np = 0; np < 4; np++) KB[np] = *(const frag8*)&Kh[(np * 16 + m) * 32 + q * 8];
      #pragma unroll
      for (int mt = 0; mt < 4; mt++)
        #pragma unroll
        for (int np = 0; np < 4; np++)
          sacc[mt][np] = __builtin_amdgcn_mfma_f32_16x16x32_bf16(QA[mt], KB[np], (f32x4){0,0,0,0}, 0, 0, 0);

      float inv[4][4];
      #pragma unroll
      for (int mt = 0; mt < 4; mt++)
        #pragma unroll
        for (int r = 0; r < 4; r++) {
          float mx = fmaxf(fmaxf(sacc[mt][0][r], sacc[mt][1][r]), fmaxf(sacc[mt][2][r], sacc[mt][3][r]));
          #pragma unroll
          for (int off = 1; off < 16; off <<= 1) mx = fmaxf(mx, __shfl_xor(mx, off));
          #pragma unroll
          for (int np = 0; np < 4; np++) sacc[mt][np][r] = __expf(sacc[mt][np][r] - mx);
          float s_ = ((sacc[mt][0][r] + sacc[mt][1][r]) + (sacc[mt][2][r] + sacc[mt][3][r]));
          #pragma unroll
          for (int off = 1; off < 16; off <<= 1) s_ += __shfl_xor(s_, off);
          inv[mt][r] = 1.f / s_;
        }

      #pragma unroll
      for (int mt = 0; mt < 4; mt++)
        #pragma unroll
        for (int np = 0; np < 4; np++) {
          u16* dst = (np < 2) ? Qh : Kh;
          int col = (np & 1) * 16 + m;
          #pragma unroll
          for (int r = 0; r < 4; r++)
            dst[(mt * 16 + q * 4 + r) * 32 + col] = f2bf(sacc[mt][np][r] * inv[mt][r]);
        }

      f32x4 oacc[4];
      #pragma unroll
      for (int mt = 0; mt < 4; mt++) oacc[mt] = (f32x4){0,0,0,0};
      #pragma unroll
      for (int kc = 0; kc < 2; kc++) {
        frag8 VB = *(const frag8*)&Vh[m * 80 + kc * 32 + q * 8];
        const u16* Psrc = kc ? Kh : Qh;
        #pragma unroll
        for (int mt = 0; mt < 4; mt++) {
          frag8 PA = *(const frag8*)&Psrc[(mt * 16 + m) * 32 + q * 8];
          oacc[mt] = __builtin_amdgcn_mfma_f32_16x16x32_bf16(PA, VB, oacc[mt], 0, 0, 0);
        }
      }
      #pragma unroll
      for (int mt = 0; mt < 4; mt++)
        #pragma unroll
        for (int r = 0; r < 4; r++)
          AOs[(mt * 16 + q * 4 + r) * 136 + wave * 16 + m] = f2bf(oacc[mt][r]);
    }
    __syncthreads();                                        // B2

    // ---- O-proj + residual into Xs ----
    {
      f32x4 ao4[4];
      #pragma unroll
      for (int mt = 0; mt < 4; mt++) ao4[mt] = (f32x4){0,0,0,0};
      gemm_pref(AOs, 136, fo, m, q, ao4);
      float bov = bo[l * 128 + n0 + m];
      #pragma unroll
      for (int mt = 0; mt < 4; mt++)
        #pragma unroll
        for (int r = 0; r < 4; r++)
          Xs[(mt * 16 + q * 4 + r) * 132 + n0 + m] += ao4[mt][r] + bov;
    }
    __syncthreads();                                        // B3

    // ---- LN2 -> Hs ----
    ln128(Xs, Hs, ln2g + l * 128, ln2b + l * 128, lane, wave);
    __syncthreads();                                        // B4

    // ---- FF1: all 4 chunks into F1s[c] (Pool), then ONE barrier ----
    {
      frag8 Ar[4][4];
      #pragma unroll
      for (int mt = 0; mt < 4; mt++)
        #pragma unroll
        for (int kc = 0; kc < 4; kc++)
          Ar[mt][kc] = *(const frag8*)&Hs[(mt * 16 + m) * 136 + kc * 32 + q * 8];
      #pragma unroll 1
      for (int c = 0; c < 4; c++) {
        f32x4 a1[4];
        #pragma unroll
        for (int mt = 0; mt < 4; mt++) a1[mt] = (f32x4){0,0,0,0};
        gemm_hoist(Ar, f1f, a1);
        if (c < 3) {
          #pragma unroll
          for (int kc = 0; kc < 4; kc++)
            f1f[kc] = *(const frag8*)(f1wb + ((c + 1) * 128 + n0 + m) * 128 + kc * 32 + q * 8);
        }
        float b1v = f1b[l * 512 + c * 128 + n0 + m];
        u16* F1c = Pool + c * 8704;
        #pragma unroll
        for (int mt = 0; mt < 4; mt++)
          #pragma unroll
          for (int r = 0; r < 4; r++)
            F1c[(mt * 16 + q * 4 + r) * 136 + n0 + m] = f2bf(geluf(a1[mt][r] + b1v));
      }
    }
    __syncthreads();                                        // B5

    // ---- FF2: all 4 chunks, barrier-free, accumulate ----
    {
      f32x4 acc2[4];
      #pragma unroll
      for (int mt = 0; mt < 4; mt++) acc2[mt] = (f32x4){0,0,0,0};
      frag8 f2f[4];
      #pragma unroll
      for (int kc = 0; kc < 4; kc++)
        f2f[kc] = *(const frag8*)(f2wb + (n0 + m) * 512 + kc * 32 + q * 8);
      #pragma unroll 1
      for (int c = 0; c < 4; c++) {
        frag8 f2n[4];
        if (c < 3) {
          #pragma unroll
          for (int kc = 0; kc < 4; kc++)
            f2n[kc] = *(const frag8*)(f2wb + (n0 + m) * 512 + (c + 1) * 128 + kc * 32 + q * 8);
        }
        gemm_pref(Pool + c * 8704, 136, f2f, m, q, acc2);
        if (c < 3) {
          #pragma unroll
          for (int kc = 0; kc < 4; kc++) f2f[kc] = f2n[kc];
        }
      }
      float b2v = f2b[l * 128 + n0 + m];
      #pragma unroll
      for (int mt = 0; mt < 4; mt++)
        #pragma unroll
        for (int r = 0; r < 4; r++)
          Xs[(mt * 16 + q * 4 + r) * 132 + n0 + m] += acc2[mt][r] + b2v;
    }
    __syncthreads();                                        // B6
  }

  for (int i = tid; i < 8192; i += 512) Xg[i] = Xs[(i >> 7) * 132 + (i & 127)];
}

// ============================================================
// k_head1 (round-1 measured config)
// ============================================================
__global__ __launch_bounds__(256) void k_head1(const float* __restrict__ X, const float* __restrict__ ew,
                                               const float* __restrict__ eb, const float* __restrict__ g3,
                                               const float* __restrict__ b3, float* __restrict__ G) {
  __shared__ float Xs[2][8192];   // 64 KB
  int b = blockIdx.x, ot = blockIdx.y;
  int tid = threadIdx.x;
  {
    const float4* x1 = (const float4*)(X + b * 8192);
    const float4* x2 = (const float4*)(X + (16 + b) * 8192);
    float4* s1 = (float4*)&Xs[0][0];
    float4* s2 = (float4*)&Xs[1][0];
    for (int i = tid; i < 2048; i += 256) { s1[i] = x1[i]; s2[i] = x2[i]; }
  }
  __syncthreads();
  int w = tid & 127, og = tid >> 7;
  int oc0 = ot * 16 + og * 8;
  float a[8] = {};
  for (int ic = 0; ic < 64; ic++) {
    float x1v = Xs[0][ic * 128 + w], x2v = Xs[1][ic * 128 + w];
    #pragma unroll
    for (int j = 0; j < 8; j++) {
      a[j] = fmaf(ew[((oc0 + j) * 64 + ic) * 2 + 0], x1v, a[j]);
      a[j] = fmaf(ew[((oc0 + j) * 64 + ic) * 2 + 1], x2v, a[j]);
    }
  }
  #pragma unroll
  for (int j = 0; j < 8; j++) {
    int oc = oc0 + j;
    float v = (a[j] + eb[oc]) * (g3[oc] * BN_S) + b3[oc];
    G[(b * 64 + oc) * 128 + w] = eluf(v);
  }
}

// ============================================================
// k_head2 (round-1 measured config)
// ============================================================
__global__ __launch_bounds__(256) void k_head2(const float* __restrict__ G, const float* __restrict__ cw,
                                               const float* __restrict__ cb, float* __restrict__ out) {
  __shared__ float red[256];
  int b = blockIdx.x, c = blockIdx.y, tid = threadIdx.x;
  const float4* g4 = (const float4*)(G + b * 8192);
  const float4* c4 = (const float4*)(cw + c * 8192);
  float p = 0.f;
  for (int i = tid; i < 2048; i += 256) {
    float4 g = g4[i], w = c4[i];
    p += g.x * w.x + g.y * w.y + g.z * w.z + g.w * w.w;
  }
  red[tid] = p;
  __syncthreads();
  for (int s = 128; s > 0; s >>= 1) {
    if (tid < s) red[tid] += red[tid + s];
    __syncthreads();
  }
  if (tid == 0) out[b * 4 + c] = red[0] + cb[c];
}

// ============================================================
extern "C" void kernel_launch(void* const* d_in, const int* in_sizes, int n_in,
                              void* d_out, int out_size, void* d_ws, size_t ws_size,
                              hipStream_t stream) {
  const float* x    = (const float*)d_in[0];
  const float* tw1  = (const float*)d_in[1];  const float* tb1 = (const float*)d_in[2];
  const float* tw2  = (const float*)d_in[3];  const float* tb2 = (const float*)d_in[4];
  const float* tw3  = (const float*)d_in[5];  const float* tb3 = (const float*)d_in[6];
  const float* tw4  = (const float*)d_in[7];  const float* tb4 = (const float*)d_in[8];
  const float* bn1g = (const float*)d_in[9];  const float* bn1b = (const float*)d_in[10];
  const float* sw   = (const float*)d_in[11]; const float* sb   = (const float*)d_in[12];
  const float* bn2g = (const float*)d_in[13]; const float* bn2b = (const float*)d_in[14];
  const float* ln1g = (const float*)d_in[15]; const float* ln1b = (const float*)d_in[16];
  const float* ln2g = (const float*)d_in[17]; const float* ln2b = (const float*)d_in[18];
  const float* wq   = (const float*)d_in[19]; const float* bq   = (const float*)d_in[20];
  const float* wk   = (const float*)d_in[21]; const float* bk   = (const float*)d_in[22];
  const float* wv   = (const float*)d_in[23]; const float* bv   = (const float*)d_in[24];
  const float* wo   = (const float*)d_in[25]; const float* bo   = (const float*)d_in[26];
  const float* f1w  = (const float*)d_in[27]; const float* f1b  = (const float*)d_in[28];
  const float* f2w  = (const float*)d_in[29]; const float* f2b  = (const float*)d_in[30];
  const float* ew   = (const float*)d_in[31]; const float* eb   = (const float*)d_in[32];
  const float* g3   = (const float*)d_in[33]; const float* b3   = (const float*)d_in[34];
  const float* cw   = (const float*)d_in[35]; const float* cb   = (const float*)d_in[36];

  float* ws      = (float*)d_ws;
  float* tws1    = ws;               // 8320
  float* c1      = ws + 8320;        // 128
  float* biasEff = ws + 8448;        // 128
  u16*   Wb      = (u16*)(ws + 8576);// 532480 bf16 [u][o][kh] (1.04 MB)
  float* z       = ws + 541056;      // 2048000 [b][o][t] partial A; reused as G after pool
  float* X       = ws + 2589056;     // 262144  [2048][128]
  u16*   Wenc    = (u16*)(ws + 3113344); // 786432 bf16 encoder weights (1.5 MB)
  float* z2      = ws + 3506560;     // 2048000 partial B
  float* G       = z;                // 131072 (z dead after k_pool)

  k_cvt6<<<768, 256, 0, stream>>>(wq, wk, wv, wo, f1w, f2w, Wenc);
  k_tws1<<<33, 256, 0, stream>>>(tw1, tw2, tw3, tw4, tb1, tb2, tb3, tb4, bn1g, bn1b, tws1, c1);
  k_weff<<<dim3(66, 32), 256, 0, stream>>>(sw, sb, tws1, c1, Wb, biasEff);
  k_conv<<<dim3(16, 4, 16), 256, 0, stream>>>(x, Wb, z, z2);
  k_pool<<<dim3(64, 16), 128, 0, stream>>>(z, z2, biasEff, bn2g, bn2b, X);

  k_enc<<<32, 512, 0, stream>>>(X, Wenc, ln1g, ln1b, ln2g, ln2b, bq, bk, bv, bo, f1b, f2b);

  k_head1<<<dim3(16, 4), 256, 0, stream>>>(X, ew, eb, g3, b3, G);
  k_head2<<<dim3(16, 4), 256, 0, stream>>>(G, cw, cb, (float*)d_out);
}

// Round 15
// 345.213 us; speedup vs baseline: 1.3100x; 1.3100x over previous
//
#include <hip/hip_runtime.h>
#include <math.h>

typedef unsigned short u16;
typedef __attribute__((ext_vector_type(8))) short frag8;   // 8 bf16 = 4 VGPR
typedef __attribute__((ext_vector_type(4))) float f32x4;   // MFMA acc

__device__ __forceinline__ float eluf(float v) { return v > 0.f ? v : expm1f(v); }
__device__ __forceinline__ float geluf(float v) {
  return 0.5f * v * (1.f + erff(v * 0.70710678118654752f));
}
__device__ __forceinline__ u16 f2bf(float f) {
  union { float f; unsigned int i; } v; v.f = f;
  return (u16)((v.i + 0x7fffu + ((v.i >> 16) & 1u)) >> 16);
}

#define BN_S 0.99999500003749969f   /* 1/sqrt(1+1e-5) */

// ============================================================
// k_tws1 (round-1 measured config)
// ============================================================
__global__ void k_tws1(const float* tw1, const float* tw2, const float* tw3, const float* tw4,
                       const float* tb1, const float* tb2, const float* tb3, const float* tb4,
                       const float* bn1g, const float* bn1b,
                       float* tws1, float* c1) {
  int idx = blockIdx.x * 256 + threadIdx.x;
  if (idx < 8320) {
    int i = idx / 65, u = idx - i * 65;
    int g = i >> 5, il = i & 31;
    const float* tws[4] = {tw1, tw2, tw3, tw4};
    const int P[4] = {7, 12, 25, 32};
    int c = u - 32;
    float s1 = bn1g[i] * BN_S;
    float val = 0.f;
    int p = P[g];
    if (c >= -p && c <= p) val = s1 * tws[g][il * (2 * p + 1) + (c + p)];
    tws1[idx] = val;
  } else if (idx < 8448) {
    int i = idx - 8320;
    int g = i >> 5, il = i & 31;
    const float* tbs[4] = {tb1, tb2, tb3, tb4};
    float s1 = bn1g[i] * BN_S;
    c1[i] = s1 * tbs[g][il] + bn1b[i];
  }
}

// ============================================================
// k_weff (round-1 measured config): one WAVE per (u, o). lane = kh.
// ============================================================
__global__ __launch_bounds__(256) void k_weff(const float* __restrict__ sw, const float* __restrict__ sb,
                                              const float* __restrict__ tws1, const float* __restrict__ c1,
                                              u16* __restrict__ Wb, float* __restrict__ biasEff) {
  const int lane = threadIdx.x & 63, wave = threadIdx.x >> 6;
  const int u = blockIdx.x;
  const int o = blockIdx.y * 4 + wave;
  const float* swp = sw + o * 8192 + lane;     // + i*64
  if (u < 65) {
    const float* tp = tws1 + u;                // + i*65 (wave-uniform)
    float a0 = 0.f, a1 = 0.f, a2 = 0.f, a3 = 0.f;
    #pragma unroll 8
    for (int i = 0; i < 128; i += 4) {
      a0 = fmaf(swp[(i + 0) * 64], tp[(i + 0) * 65], a0);
      a1 = fmaf(swp[(i + 1) * 64], tp[(i + 1) * 65], a1);
      a2 = fmaf(swp[(i + 2) * 64], tp[(i + 2) * 65], a2);
      a3 = fmaf(swp[(i + 3) * 64], tp[(i + 3) * 65], a3);
    }
    Wb[(u * 128 + o) * 64 + lane] = f2bf((a0 + a1) + (a2 + a3));
  } else {
    float pa = 0.f;
    #pragma unroll 8
    for (int i = 0; i < 128; i++)
      pa = fmaf(swp[i * 64], c1[i], pa);
    #pragma unroll
    for (int off = 32; off; off >>= 1) pa += __shfl_xor(pa, off);
    if (lane == 0) biasEff[o] = pa + sb[o];
  }
}

// ============================================================
// k_conv: r1 tiles/staging (o64, grid (16,2,16)) + B-fragment
// register double-buffer. Bit-identical math (measured r11).
// ============================================================
__global__ __launch_bounds__(256) void k_conv(const float* __restrict__ x,
                                              const u16* __restrict__ Wb,
                                              const float* __restrict__ biasEff,
                                              const float* __restrict__ bn2g, const float* __restrict__ bn2b,
                                              float* __restrict__ z) {
  __shared__ u16 xs[128 * 88];   // 22.5 KB; row tt -> t0-32+tt, col kh
  const int tid = threadIdx.x;
  const int t0 = blockIdx.x * 64;
  const int o0 = blockIdx.y * 64;
  const int b  = blockIdx.z;

  #pragma unroll
  for (int i = 0; i < 8; i++) {
    int pos = tid + i * 256;
    int kh = pos >> 5;
    int tt = (pos & 31) * 4;
    int gt = t0 - 32 + tt;
    const float* xp = x + (b * 64 + kh) * 1000;
    float v[4];
    if (gt >= 0 && gt + 3 < 1000) {
      float4 f = *(const float4*)(xp + gt);
      v[0] = f.x; v[1] = f.y; v[2] = f.z; v[3] = f.w;
    } else {
      #pragma unroll
      for (int e = 0; e < 4; e++) { int g2 = gt + e; v[e] = (g2 >= 0 && g2 < 1000) ? xp[g2] : 0.f; }
    }
    #pragma unroll
    for (int e = 0; e < 4; e++) xs[(tt + e) * 88 + kh] = f2bf(v[e]);
  }
  __syncthreads();

  const int lane = tid & 63, wave = tid >> 6;
  const int wt = (wave & 1) * 32;
  const int wo = (wave >> 1) * 32;
  const int m = lane & 15, q = lane >> 4;

  f32x4 acc[2][2];
  #pragma unroll
  for (int i = 0; i < 2; i++)
    #pragma unroll
    for (int j = 0; j < 2; j++) acc[i][j] = (f32x4){0.f, 0.f, 0.f, 0.f};

  frag8 Bc[2][2];
  #pragma unroll
  for (int op = 0; op < 2; op++)
    #pragma unroll
    for (int kc = 0; kc < 2; kc++)
      Bc[op][kc] = *(const frag8*)(Wb + (o0 + wo + op * 16 + m) * 64 + kc * 32 + q * 8);

  #pragma unroll 1
  for (int u = 0; u < 65; u++) {
    frag8 Bn[2][2];
    int un = (u < 64) ? u + 1 : 64;     // harmless re-load on last iter
    #pragma unroll
    for (int op = 0; op < 2; op++)
      #pragma unroll
      for (int kc = 0; kc < 2; kc++)
        Bn[op][kc] = *(const frag8*)(Wb + ((un * 128) + o0 + wo + op * 16 + m) * 64 + kc * 32 + q * 8);
    frag8 A[2][2];
    #pragma unroll
    for (int tp = 0; tp < 2; tp++)
      #pragma unroll
      for (int kc = 0; kc < 2; kc++)
        A[tp][kc] = *(const frag8*)&xs[(wt + tp * 16 + m + u) * 88 + kc * 32 + q * 8];
    #pragma unroll
    for (int tp = 0; tp < 2; tp++)
      #pragma unroll
      for (int op = 0; op < 2; op++) {
        acc[tp][op] = __builtin_amdgcn_mfma_f32_16x16x32_bf16(A[tp][0], Bc[op][0], acc[tp][op], 0, 0, 0);
        acc[tp][op] = __builtin_amdgcn_mfma_f32_16x16x32_bf16(A[tp][1], Bc[op][1], acc[tp][op], 0, 0, 0);
      }
    #pragma unroll
    for (int op = 0; op < 2; op++)
      #pragma unroll
      for (int kc = 0; kc < 2; kc++)
        Bc[op][kc] = Bn[op][kc];
  }

  #pragma unroll
  for (int op = 0; op < 2; op++) {
    int o = o0 + wo + op * 16 + m;
    float s2 = bn2g[o] * BN_S;
    float be = biasEff[o], b2 = bn2b[o];
    #pragma unroll
    for (int tp = 0; tp < 2; tp++) {
      #pragma unroll
      for (int r = 0; r < 4; r++) {
        int t = t0 + wt + tp * 16 + q * 4 + r;
        if (t < 1000)
          z[(b * 128 + o) * 1000 + t] = eluf((acc[tp][op][r] + be) * s2 + b2);
      }
    }
  }
}

// ============================================================
// k_pool (round-1 measured config)
// ============================================================
__global__ __launch_bounds__(128) void k_pool(const float* __restrict__ z, float* __restrict__ X) {
  int p = blockIdx.x, b = blockIdx.y, o = threadIdx.x;
  const float* zp = z + (b * 128 + o) * 1000 + p * 15;
  float s = 0.f, ss = 0.f;
  #pragma unroll
  for (int k = 0; k < 50; k++) { float v = zp[k]; s += v; ss = fmaf(v, v, ss); }
  float m = s * 0.02f;
  float var = (ss - s * m) * (1.f / 49.f);
  var = fminf(fmaxf(var, 1e-6f), 1e6f);
  X[(b * 64 + p) * 128 + o] = m;
  X[((16 + b) * 64 + p) * 128 + o] = logf(var);
}

// ============================================================
// k_cvt6 (round-1 measured config): encoder weights f32 -> bf16
// ============================================================
__global__ __launch_bounds__(256) void k_cvt6(const float* __restrict__ wq, const float* __restrict__ wk,
                                              const float* __restrict__ wv, const float* __restrict__ wo,
                                              const float* __restrict__ f1w, const float* __restrict__ f2w,
                                              u16* __restrict__ out) {
  int i = blockIdx.x * 256 + threadIdx.x;   // float4 index, total 196608
  if (i >= 196608) return;
  int fi = i * 4;
  const float* src; int off;
  if      (fi < 65536)  { src = wq;  off = fi; }
  else if (fi < 131072) { src = wk;  off = fi - 65536; }
  else if (fi < 196608) { src = wv;  off = fi - 131072; }
  else if (fi < 262144) { src = wo;  off = fi - 196608; }
  else if (fi < 524288) { src = f1w; off = fi - 262144; }
  else                  { src = f2w; off = fi - 524288; }
  float4 v = *(const float4*)(src + off);
  ushort4 p;
  p.x = f2bf(v.x); p.y = f2bf(v.y); p.z = f2bf(v.z); p.w = f2bf(v.w);
  *(ushort4*)(out + fi) = p;
}

// ============================================================
// k_enc (round-8 measured config, 115.5 us): fused 4-layer encoder,
// 32 blocks x 512 threads. MFMA attention; 6 barriers/layer.
// LDS (137.2 KB): Xs f32[64][132] | Hs bf16[64][136] | Pool u16[43008]
// ============================================================
__device__ __forceinline__ void ln128(const float* __restrict__ Xs, u16* __restrict__ Hs,
                                      const float* __restrict__ g, const float* __restrict__ b,
                                      int lane, int wave) {
  float g0 = g[lane], g1 = g[64 + lane], b0 = b[lane], b1 = b[64 + lane];
  #pragma unroll
  for (int rr = 0; rr < 8; rr++) {
    int r = wave * 8 + rr;
    float v0 = Xs[r * 132 + lane], v1 = Xs[r * 132 + 64 + lane];
    float s_ = v0 + v1;
    #pragma unroll
    for (int off = 32; off; off >>= 1) s_ += __shfl_xor(s_, off);
    float mn = s_ * (1.f / 128.f);
    float d0 = v0 - mn, d1 = v1 - mn;
    float qq = d0 * d0 + d1 * d1;
    #pragma unroll
    for (int off = 32; off; off >>= 1) qq += __shfl_xor(qq, off);
    float rs = rsqrtf(qq * (1.f / 128.f) + 1e-5f);
    Hs[r * 136 + lane]      = f2bf(d0 * rs * g0 + b0);
    Hs[r * 136 + 64 + lane] = f2bf(d1 * rs * g1 + b1);
  }
}

__device__ __forceinline__ void gemm_hoist(const frag8 Ar[4][4], const frag8 Bf[4], f32x4 acc[4]) {
  #pragma unroll
  for (int kc = 0; kc < 4; kc++)
    #pragma unroll
    for (int mt = 0; mt < 4; mt++)
      acc[mt] = __builtin_amdgcn_mfma_f32_16x16x32_bf16(Ar[mt][kc], Bf[kc], acc[mt], 0, 0, 0);
}

__device__ __forceinline__ void gemm_pref(const u16* __restrict__ Asrc, int astride,
                                          const frag8 Bf[4], int m, int q, f32x4 acc[4]) {
  #pragma unroll
  for (int kc = 0; kc < 4; kc++) {
    #pragma unroll
    for (int mt = 0; mt < 4; mt++) {
      frag8 Af = *(const frag8*)(Asrc + (mt * 16 + m) * astride + kc * 32 + q * 8);
      acc[mt] = __builtin_amdgcn_mfma_f32_16x16x32_bf16(Af, Bf[kc], acc[mt], 0, 0, 0);
    }
  }
}

__global__ __launch_bounds__(512, 1) void k_enc(float* __restrict__ X,
                                                const u16* __restrict__ Wenc,
                                                const float* __restrict__ ln1g, const float* __restrict__ ln1b,
                                                const float* __restrict__ ln2g, const float* __restrict__ ln2b,
                                                const float* __restrict__ bq, const float* __restrict__ bk,
                                                const float* __restrict__ bv, const float* __restrict__ bo,
                                                const float* __restrict__ f1b, const float* __restrict__ f2b) {
  __shared__ __align__(16) float Xs[64 * 132];
  __shared__ __align__(16) u16   Hs[64 * 136];
  __shared__ __align__(16) u16   Pool[43008];
  u16* AOs = Hs;

  const int tid = threadIdx.x;
  const int lane = tid & 63, wave = tid >> 6;
  const int m = lane & 15, q = lane >> 4;
  const int n0 = wave * 16;
  float* Xg = X + blockIdx.x * 64 * 128;

  const u16* WQ  = Wenc;
  const u16* WK  = Wenc + 65536;
  const u16* WV  = Wenc + 131072;
  const u16* WO  = Wenc + 196608;
  const u16* F1W = Wenc + 262144;
  const u16* F2W = Wenc + 524288;

  u16* Qh = Pool + wave * 2048;            // [64][32], zero-padded K
  u16* Kh = Pool + 16384 + wave * 2048;    // [64][32]
  u16* Vh = Pool + 32768 + wave * 1280;    // [16][80] transposed V

  for (int i = tid; i < 8192; i += 512) Xs[(i >> 7) * 132 + (i & 127)] = Xg[i];
  __syncthreads();

  #pragma unroll 1
  for (int l = 0; l < 4; l++) {
    const u16* wqb  = WQ  + l * 16384;
    const u16* wkb  = WK  + l * 16384;
    const u16* wvb  = WV  + l * 16384;
    const u16* wob  = WO  + l * 16384;
    const u16* f1wb = F1W + l * 65536;
    const u16* f2wb = F2W + l * 65536;

    // ---- prefetch QKV B-frags (hide under LN1) ----
    frag8 fq[4], fk[4], fv[4];
    #pragma unroll
    for (int kc = 0; kc < 4; kc++) {
      fq[kc] = *(const frag8*)(wqb + (n0 + m) * 128 + kc * 32 + q * 8);
      fk[kc] = *(const frag8*)(wkb + (n0 + m) * 128 + kc * 32 + q * 8);
      fv[kc] = *(const frag8*)(wvb + (n0 + m) * 128 + kc * 32 + q * 8);
    }

    // ---- LN1 -> Hs ----
    ln128(Xs, Hs, ln1g + l * 128, ln1b + l * 128, lane, wave);
    __syncthreads();                                        // B1

    // ---- QKV gemms (A hoisted) + bf16 stores into head buffers ----
    frag8 fo[4];
    #pragma unroll
    for (int kc = 0; kc < 4; kc++)
      fo[kc] = *(const frag8*)(wob + (n0 + m) * 128 + kc * 32 + q * 8);
    {
      frag8 Ar[4][4];
      #pragma unroll
      for (int mt = 0; mt < 4; mt++)
        #pragma unroll
        for (int kc = 0; kc < 4; kc++)
          Ar[mt][kc] = *(const frag8*)&Hs[(mt * 16 + m) * 136 + kc * 32 + q * 8];
      f32x4 aq[4], ak[4], av[4];
      #pragma unroll
      for (int mt = 0; mt < 4; mt++) { aq[mt] = (f32x4){0,0,0,0}; ak[mt] = (f32x4){0,0,0,0}; av[mt] = (f32x4){0,0,0,0}; }
      gemm_hoist(Ar, fq, aq);
      gemm_hoist(Ar, fk, ak);
      gemm_hoist(Ar, fv, av);
      float bqv = bq[l * 128 + n0 + m];
      float bkv = bk[l * 128 + n0 + m];
      float bvv = bv[l * 128 + n0 + m];
      #pragma unroll
      for (int mt = 0; mt < 4; mt++)
        #pragma unroll
        for (int r = 0; r < 4; r++) {
          int row = mt * 16 + q * 4 + r;
          Qh[row * 32 + m] = f2bf((aq[mt][r] + bqv) * 0.25f);  // fold 1/sqrt(dk), exact
          Kh[row * 32 + m] = f2bf(ak[mt][r] + bkv);
          Vh[m * 80 + row] = f2bf(av[mt][r] + bvv);            // V transposed [d][key]
        }
      frag8 z8 = {};
      *(frag8*)&Qh[lane * 32 + 16] = z8;
      *(frag8*)&Qh[lane * 32 + 24] = z8;
      *(frag8*)&Kh[lane * 32 + 16] = z8;
      *(frag8*)&Kh[lane * 32 + 24] = z8;
    }

    // ---- attention (wave-local head; no barrier since QKV) ----
    frag8 f1f[4];
    #pragma unroll
    for (int kc = 0; kc < 4; kc++)
      f1f[kc] = *(const frag8*)(f1wb + (n0 + m) * 128 + kc * 32 + q * 8);
    {
      f32x4 sacc[4][4];
      frag8 QA[4], KB[4];
      #pragma unroll
      for (int mt = 0; mt < 4; mt++) QA[mt] = *(const frag8*)&Qh[(mt * 16 + m) * 32 + q * 8];
      #pragma unroll
      for (int np = 0; np < 4; np++) KB[np] = *(const frag8*)&Kh[(np * 16 + m) * 32 + q * 8];
      #pragma unroll
      for (int mt = 0; mt < 4; mt++)
        #pragma unroll
        for (int np = 0; np < 4; np++)
          sacc[mt][np] = __builtin_amdgcn_mfma_f32_16x16x32_bf16(QA[mt], KB[np], (f32x4){0,0,0,0}, 0, 0, 0);

      float inv[4][4];
      #pragma unroll
      for (int mt = 0; mt < 4; mt++)
        #pragma unroll
        for (int r = 0; r < 4; r++) {
          float mx = fmaxf(fmaxf(sacc[mt][0][r], sacc[mt][1][r]), fmaxf(sacc[mt][2][r], sacc[mt][3][r]));
          #pragma unroll
          for (int off = 1; off < 16; off <<= 1) mx = fmaxf(mx, __shfl_xor(mx, off));
          #pragma unroll
          for (int np = 0; np < 4; np++) sacc[mt][np][r] = __expf(sacc[mt][np][r] - mx);
          float s_ = ((sacc[mt][0][r] + sacc[mt][1][r]) + (sacc[mt][2][r] + sacc[mt][3][r]));
          #pragma unroll
          for (int off = 1; off < 16; off <<= 1) s_ += __shfl_xor(s_, off);
          inv[mt][r] = 1.f / s_;
        }

      #pragma unroll
      for (int mt = 0; mt < 4; mt++)
        #pragma unroll
        for (int np = 0; np < 4; np++) {
          u16* dst = (np < 2) ? Qh : Kh;
          int col = (np & 1) * 16 + m;
          #pragma unroll
          for (int r = 0; r < 4; r++)
            dst[(mt * 16 + q * 4 + r) * 32 + col] = f2bf(sacc[mt][np][r] * inv[mt][r]);
        }

      f32x4 oacc[4];
      #pragma unroll
      for (int mt = 0; mt < 4; mt++) oacc[mt] = (f32x4){0,0,0,0};
      #pragma unroll
      for (int kc = 0; kc < 2; kc++) {
        frag8 VB = *(const frag8*)&Vh[m * 80 + kc * 32 + q * 8];
        const u16* Psrc = kc ? Kh : Qh;
        #pragma unroll
        for (int mt = 0; mt < 4; mt++) {
          frag8 PA = *(const frag8*)&Psrc[(mt * 16 + m) * 32 + q * 8];
          oacc[mt] = __builtin_amdgcn_mfma_f32_16x16x32_bf16(PA, VB, oacc[mt], 0, 0, 0);
        }
      }
      #pragma unroll
      for (int mt = 0; mt < 4; mt++)
        #pragma unroll
        for (int r = 0; r < 4; r++)
          AOs[(mt * 16 + q * 4 + r) * 136 + wave * 16 + m] = f2bf(oacc[mt][r]);
    }
    __syncthreads();                                        // B2

    // ---- O-proj + residual into Xs ----
    {
      f32x4 ao4[4];
      #pragma unroll
      for (int mt = 0; mt < 4; mt++) ao4[mt] = (f32x4){0,0,0,0};
      gemm_pref(AOs, 136, fo, m, q, ao4);
      float bov = bo[l * 128 + n0 + m];
      #pragma unroll
      for (int mt = 0; mt < 4; mt++)
        #pragma unroll
        for (int r = 0; r < 4; r++)
          Xs[(mt * 16 + q * 4 + r) * 132 + n0 + m] += ao4[mt][r] + bov;
    }
    __syncthreads();                                        // B3

    // ---- LN2 -> Hs ----
    ln128(Xs, Hs, ln2g + l * 128, ln2b + l * 128, lane, wave);
    __syncthreads();                                        // B4

    // ---- FF1: all 4 chunks into F1s[c] (Pool), then ONE barrier ----
    {
      frag8 Ar[4][4];
      #pragma unroll
      for (int mt = 0; mt < 4; mt++)
        #pragma unroll
        for (int kc = 0; kc < 4; kc++)
          Ar[mt][kc] = *(const frag8*)&Hs[(mt * 16 + m) * 136 + kc * 32 + q * 8];
      #pragma unroll 1
      for (int c = 0; c < 4; c++) {
        f32x4 a1[4];
        #pragma unroll
        for (int mt = 0; mt < 4; mt++) a1[mt] = (f32x4){0,0,0,0};
        gemm_hoist(Ar, f1f, a1);
        if (c < 3) {
          #pragma unroll
          for (int kc = 0; kc < 4; kc++)
            f1f[kc] = *(const frag8*)(f1wb + ((c + 1) * 128 + n0 + m) * 128 + kc * 32 + q * 8);
        }
        float b1v = f1b[l * 512 + c * 128 + n0 + m];
        u16* F1c = Pool + c * 8704;
        #pragma unroll
        for (int mt = 0; mt < 4; mt++)
          #pragma unroll
          for (int r = 0; r < 4; r++)
            F1c[(mt * 16 + q * 4 + r) * 136 + n0 + m] = f2bf(geluf(a1[mt][r] + b1v));
      }
    }
    __syncthreads();                                        // B5

    // ---- FF2: all 4 chunks, barrier-free, accumulate ----
    {
      f32x4 acc2[4];
      #pragma unroll
      for (int mt = 0; mt < 4; mt++) acc2[mt] = (f32x4){0,0,0,0};
      frag8 f2f[4];
      #pragma unroll
      for (int kc = 0; kc < 4; kc++)
        f2f[kc] = *(const frag8*)(f2wb + (n0 + m) * 512 + kc * 32 + q * 8);
      #pragma unroll 1
      for (int c = 0; c < 4; c++) {
        frag8 f2n[4];
        if (c < 3) {
          #pragma unroll
          for (int kc = 0; kc < 4; kc++)
            f2n[kc] = *(const frag8*)(f2wb + (n0 + m) * 512 + (c + 1) * 128 + kc * 32 + q * 8);
        }
        gemm_pref(Pool + c * 8704, 136, f2f, m, q, acc2);
        if (c < 3) {
          #pragma unroll
          for (int kc = 0; kc < 4; kc++) f2f[kc] = f2n[kc];
        }
      }
      float b2v = f2b[l * 128 + n0 + m];
      #pragma unroll
      for (int mt = 0; mt < 4; mt++)
        #pragma unroll
        for (int r = 0; r < 4; r++)
          Xs[(mt * 16 + q * 4 + r) * 132 + n0 + m] += acc2[mt][r] + b2v;
    }
    __syncthreads();                                        // B6
  }

  for (int i = tid; i < 8192; i += 512) Xg[i] = Xs[(i >> 7) * 132 + (i & 127)];
}

// ============================================================
// k_head1 (round-1 measured config)
// ============================================================
__global__ __launch_bounds__(256) void k_head1(const float* __restrict__ X, const float* __restrict__ ew,
                                               const float* __restrict__ eb, const float* __restrict__ g3,
                                               const float* __restrict__ b3, float* __restrict__ G) {
  __shared__ float Xs[2][8192];   // 64 KB
  int b = blockIdx.x, ot = blockIdx.y;
  int tid = threadIdx.x;
  {
    const float4* x1 = (const float4*)(X + b * 8192);
    const float4* x2 = (const float4*)(X + (16 + b) * 8192);
    float4* s1 = (float4*)&Xs[0][0];
    float4* s2 = (float4*)&Xs[1][0];
    for (int i = tid; i < 2048; i += 256) { s1[i] = x1[i]; s2[i] = x2[i]; }
  }
  __syncthreads();
  int w = tid & 127, og = tid >> 7;
  int oc0 = ot * 16 + og * 8;
  float a[8] = {};
  for (int ic = 0; ic < 64; ic++) {
    float x1v = Xs[0][ic * 128 + w], x2v = Xs[1][ic * 128 + w];
    #pragma unroll
    for (int j = 0; j < 8; j++) {
      a[j] = fmaf(ew[((oc0 + j) * 64 + ic) * 2 + 0], x1v, a[j]);
      a[j] = fmaf(ew[((oc0 + j) * 64 + ic) * 2 + 1], x2v, a[j]);
    }
  }
  #pragma unroll
  for (int j = 0; j < 8; j++) {
    int oc = oc0 + j;
    float v = (a[j] + eb[oc]) * (g3[oc] * BN_S) + b3[oc];
    G[(b * 64 + oc) * 128 + w] = eluf(v);
  }
}

// ============================================================
// k_head2 (round-1 measured config)
// ============================================================
__global__ __launch_bounds__(256) void k_head2(const float* __restrict__ G, const float* __restrict__ cw,
                                               const float* __restrict__ cb, float* __restrict__ out) {
  __shared__ float red[256];
  int b = blockIdx.x, c = blockIdx.y, tid = threadIdx.x;
  const float4* g4 = (const float4*)(G + b * 8192);
  const float4* c4 = (const float4*)(cw + c * 8192);
  float p = 0.f;
  for (int i = tid; i < 2048; i += 256) {
    float4 g = g4[i], w = c4[i];
    p += g.x * w.x + g.y * w.y + g.z * w.z + g.w * w.w;
  }
  red[tid] = p;
  __syncthreads();
  for (int s = 128; s > 0; s >>= 1) {
    if (tid < s) red[tid] += red[tid + s];
    __syncthreads();
  }
  if (tid == 0) out[b * 4 + c] = red[0] + cb[c];
}

// ============================================================
extern "C" void kernel_launch(void* const* d_in, const int* in_sizes, int n_in,
                              void* d_out, int out_size, void* d_ws, size_t ws_size,
                              hipStream_t stream) {
  const float* x    = (const float*)d_in[0];
  const float* tw1  = (const float*)d_in[1];  const float* tb1 = (const float*)d_in[2];
  const float* tw2  = (const float*)d_in[3];  const float* tb2 = (const float*)d_in[4];
  const float* tw3  = (const float*)d_in[5];  const float* tb3 = (const float*)d_in[6];
  const float* tw4  = (const float*)d_in[7];  const float* tb4 = (const float*)d_in[8];
  const float* bn1g = (const float*)d_in[9];  const float* bn1b = (const float*)d_in[10];
  const float* sw   = (const float*)d_in[11]; const float* sb   = (const float*)d_in[12];
  const float* bn2g = (const float*)d_in[13]; const float* bn2b = (const float*)d_in[14];
  const float* ln1g = (const float*)d_in[15]; const float* ln1b = (const float*)d_in[16];
  const float* ln2g = (const float*)d_in[17]; const float* ln2b = (const float*)d_in[18];
  const float* wq   = (const float*)d_in[19]; const float* bq   = (const float*)d_in[20];
  const float* wk   = (const float*)d_in[21]; const float* bk   = (const float*)d_in[22];
  const float* wv   = (const float*)d_in[23]; const float* bv   = (const float*)d_in[24];
  const float* wo   = (const float*)d_in[25]; const float* bo   = (const float*)d_in[26];
  const float* f1w  = (const float*)d_in[27]; const float* f1b  = (const float*)d_in[28];
  const float* f2w  = (const float*)d_in[29]; const float* f2b  = (const float*)d_in[30];
  const float* ew   = (const float*)d_in[31]; const float* eb   = (const float*)d_in[32];
  const float* g3   = (const float*)d_in[33]; const float* b3   = (const float*)d_in[34];
  const float* cw   = (const float*)d_in[35]; const float* cb   = (const float*)d_in[36];

  float* ws      = (float*)d_ws;
  float* tws1    = ws;               // 8320
  float* c1      = ws + 8320;        // 128
  float* biasEff = ws + 8448;        // 128
  u16*   Wb      = (u16*)(ws + 8576);// 532480 bf16 [u][o][kh] (1.04 MB)
  float* z       = ws + 541056;      // 2048000 [b][o][t]; reused as G after pool
  float* X       = ws + 2589056;     // 262144  [2048][128]
  u16*   Wenc    = (u16*)(ws + 3113344); // 786432 bf16 encoder weights (1.5 MB)
  float* G       = z;                // 131072 (z dead after k_pool)

  k_cvt6<<<768, 256, 0, stream>>>(wq, wk, wv, wo, f1w, f2w, Wenc);
  k_tws1<<<33, 256, 0, stream>>>(tw1, tw2, tw3, tw4, tb1, tb2, tb3, tb4, bn1g, bn1b, tws1, c1);
  k_weff<<<dim3(66, 32), 256, 0, stream>>>(sw, sb, tws1, c1, Wb, biasEff);
  k_conv<<<dim3(16, 2, 16), 256, 0, stream>>>(x, Wb, biasEff, bn2g, bn2b, z);
  k_pool<<<dim3(64, 16), 128, 0, stream>>>(z, X);

  k_enc<<<32, 512, 0, stream>>>(X, Wenc, ln1g, ln1b, ln2g, ln2b, bq, bk, bv, bo, f1b, f2b);

  k_head1<<<dim3(16, 4), 256, 0, stream>>>(X, ew, eb, g3, b3, G);
  k_head2<<<dim3(16, 4), 256, 0, stream>>>(G, cw, cb, (float*)d_out);
}